// Round 1
// baseline (365.273 us; speedup 1.0000x reference)
//
#include <hip/hip_runtime.h>
#include <math.h>

#define N_NODES 50000
#define N_EDGES 500000
#define DIM     128
#define NGRAPH  50
#define NPGC    1000
#define KSEL    500
#define SCAN_B  1024
#define SORT_N  1024

// ---------------- degree / dinv (f64 scoring path) ----------------

__global__ void deg_kernel(const int* __restrict__ dst, int* __restrict__ deg) {
    int e = blockIdx.x * blockDim.x + threadIdx.x;
    if (e < N_EDGES) atomicAdd(&deg[dst[e]], 1);
}

__global__ void dinv_kernel(const int* __restrict__ deg, double* __restrict__ dinv) {
    int i = blockIdx.x * blockDim.x + threadIdx.x;
    if (i < N_NODES) dinv[i] = 1.0 / sqrt((double)(deg[i] + 1));
}

// ---------------- per-node dots: xw_s = x.W_s, sf = x.W_f + b_f ----------------
// one 64-lane wave per node; lane l covers k=l and k=l+64; f64 accumulate.

__global__ void dots_kernel(const float* __restrict__ x, const float* __restrict__ Ws,
                            const float* __restrict__ Wf, const float* __restrict__ bf,
                            double* __restrict__ xw_s, double* __restrict__ sf) {
    int gid  = blockIdx.x * blockDim.x + threadIdx.x;
    int wave = gid >> 6;
    int lane = threadIdx.x & 63;
    if (wave >= N_NODES) return;
    const float* xr = x + (size_t)wave * DIM;
    double x1 = (double)xr[lane], x2 = (double)xr[lane + 64];
    double ps = x1 * (double)Ws[lane] + x2 * (double)Ws[lane + 64];
    double pf = x1 * (double)Wf[lane] + x2 * (double)Wf[lane + 64];
    for (int off = 32; off > 0; off >>= 1) {
        ps += __shfl_down(ps, off, 64);
        pf += __shfl_down(pf, off, 64);
    }
    if (lane == 0) { xw_s[wave] = ps; sf[wave] = pf + (double)bf[0]; }
}

// ---------------- structure-score edge aggregation (f64 atomics) ----------------

__global__ void score_edge_kernel(const int* __restrict__ src, const int* __restrict__ dst,
                                  const double* __restrict__ dinv, const double* __restrict__ xw_s,
                                  double* __restrict__ score_sd) {
    int e = blockIdx.x * blockDim.x + threadIdx.x;
    if (e >= N_EDGES) return;
    int s = src[e], d = dst[e];
    atomicAdd(&score_sd[d], dinv[s] * dinv[d] * xw_s[s]);
}

__global__ void score_finalize_kernel(const double* __restrict__ dinv, const double* __restrict__ xw_s,
                                      const double* __restrict__ sf, const float* __restrict__ bs,
                                      double* __restrict__ score_sd, float* __restrict__ scoref) {
    int i = blockIdx.x * blockDim.x + threadIdx.x;
    if (i >= N_NODES) return;
    const double A = 0.6, OMA = 1.0 - 0.6;
    double di  = dinv[i];
    double tot = score_sd[i] + di * di * xw_s[i] + (double)bs[0];  // + self loop + b_s
    double val = tanh(A * tot + OMA * sf[i]);
    score_sd[i] = val;          // reuse buffer as final f64 score (sort key)
    scoref[i]   = (float)val;   // f32 multiplier
}

// ---------------- per-graph top-k via bitonic sort (f64 keys, stable ties) ----------------

__global__ __launch_bounds__(512) void topk_kernel(const double* __restrict__ score_d,
                                                   const int* __restrict__ batch,
                                                   int* __restrict__ perm, int* __restrict__ nodemap,
                                                   float* __restrict__ out, long o2, long o3) {
    __shared__ double key[SORT_N];
    __shared__ int    idx[SORT_N];
    int g = blockIdx.x, t = threadIdx.x;
    for (int i = t; i < SORT_N; i += 512) {
        if (i < NPGC) { key[i] = score_d[(size_t)g * NPGC + i]; idx[i] = i; }
        else          { key[i] = -1e300;                        idx[i] = i; }
    }
    __syncthreads();
    for (int size = 2; size <= SORT_N; size <<= 1) {
        for (int stride = size >> 1; stride > 0; stride >>= 1) {
            int a = ((t & ~(stride - 1)) << 1) | (t & (stride - 1));
            int b = a | stride;
            bool descFirst = ((a & size) == 0);
            double ka = key[a], kb = key[b];
            int ia = idx[a], ib = idx[b];
            // "a belongs after b" in descending order (stable: ties by lower index first)
            bool aAfterB = (ka < kb) || (ka == kb && ia > ib);
            if (descFirst ? aAfterB : !aAfterB) {
                key[a] = kb; key[b] = ka;
                idx[a] = ib; idx[b] = ia;
            }
            __syncthreads();
        }
    }
    for (int j = t; j < KSEL; j += 512) {
        int node = g * NPGC + idx[j];
        int pos  = g * KSEL + j;
        perm[pos]     = node;
        nodemap[node] = pos;
        out[o2 + pos] = (float)batch[node];  // batch_out
        out[o3 + pos] = (float)node;         // perm
    }
}

// ---------------- stable edge compaction: flags -> scan -> scatter ----------------

__global__ void edge_flags_kernel(const int* __restrict__ src, const int* __restrict__ dst,
                                  const int* __restrict__ nodemap, int* __restrict__ flags) {
    int e = blockIdx.x * blockDim.x + threadIdx.x;
    if (e < N_EDGES) flags[e] = (nodemap[src[e]] >= 0 && nodemap[dst[e]] >= 0) ? 1 : 0;
}

__global__ __launch_bounds__(SCAN_B) void scan_block_kernel(const int* __restrict__ in,
                                                            int* __restrict__ out,
                                                            int* __restrict__ bsums, int n) {
    __shared__ int s[SCAN_B];
    int t = threadIdx.x, g = blockIdx.x * SCAN_B + t;
    int v = (g < n) ? in[g] : 0;
    s[t] = v; __syncthreads();
    for (int off = 1; off < SCAN_B; off <<= 1) {
        int u = (t >= off) ? s[t - off] : 0;
        __syncthreads();
        s[t] += u;
        __syncthreads();
    }
    if (g < n) out[g] = s[t] - v;                 // exclusive within block
    if (t == SCAN_B - 1) bsums[blockIdx.x] = s[t];
}

__global__ __launch_bounds__(SCAN_B) void scan_sums_kernel(int* __restrict__ bsums, int nb) {
    __shared__ int s[SCAN_B];
    int t = threadIdx.x;
    int v = (t < nb) ? bsums[t] : 0;
    s[t] = v; __syncthreads();
    for (int off = 1; off < SCAN_B; off <<= 1) {
        int u = (t >= off) ? s[t - off] : 0;
        __syncthreads();
        s[t] += u;
        __syncthreads();
    }
    if (t < nb) bsums[t] = s[t] - v;              // exclusive
}

__global__ void scan_add_kernel(int* __restrict__ out, const int* __restrict__ bsums, int n) {
    int g = blockIdx.x * blockDim.x + threadIdx.x;
    if (g < n) out[g] += bsums[g / SCAN_B];
}

__global__ void edge_scatter_kernel(const int* __restrict__ src, const int* __restrict__ dst,
                                    const int* __restrict__ nodemap, const int* __restrict__ epos,
                                    float* __restrict__ out_edges, long M) {
    int e = blockIdx.x * blockDim.x + threadIdx.x;
    if (e >= N_EDGES) return;
    int r = nodemap[src[e]], c = nodemap[dst[e]];
    if (r >= 0 && c >= 0) {
        int pos = epos[e];
        out_edges[pos]     = (float)r;
        out_edges[M + pos] = (float)c;
    }
}

// ---------------- CSR by dst ----------------

__global__ void csr_fill_kernel(const int* __restrict__ src, const int* __restrict__ dst,
                                const int* __restrict__ rowoff, int* __restrict__ cursor,
                                int* __restrict__ csr_src) {
    int e = blockIdx.x * blockDim.x + threadIdx.x;
    if (e >= N_EDGES) return;
    int d = dst[e];
    int pos = rowoff[d] + atomicAdd(&cursor[d], 1);
    csr_src[pos] = src[e];
}

// ---------------- xw = x @ W_fu (fp32, W in LDS) ----------------
// block: 256 threads, 64 nodes. thread: 8 nodes x 4 channels, k unrolled x4.

__global__ __launch_bounds__(256) void gemm_xw_kernel(const float* __restrict__ x,
                                                      const float* __restrict__ W,
                                                      float* __restrict__ xw) {
    __shared__ float Ws[DIM * DIM];
    int t = threadIdx.x;
    { // stage W: 16384 floats, coalesced float4
        const float4* Wv = (const float4*)W;
        float4* Lv = (float4*)Ws;
        for (int i = t; i < DIM * DIM / 4; i += 256) Lv[i] = Wv[i];
    }
    __syncthreads();
    int ch    = (t & 31) * 4;
    int node0 = blockIdx.x * 64 + (t >> 5) * 8;
    float4 acc[8];
    #pragma unroll
    for (int nn = 0; nn < 8; nn++) acc[nn] = make_float4(0.f, 0.f, 0.f, 0.f);

    for (int k = 0; k < DIM; k += 4) {
        float4 w0 = *(const float4*)&Ws[(k + 0) * DIM + ch];
        float4 w1 = *(const float4*)&Ws[(k + 1) * DIM + ch];
        float4 w2 = *(const float4*)&Ws[(k + 2) * DIM + ch];
        float4 w3 = *(const float4*)&Ws[(k + 3) * DIM + ch];
        #pragma unroll
        for (int nn = 0; nn < 8; nn++) {
            int node = node0 + nn;
            if (node < N_NODES) {
                float4 xv = *(const float4*)&x[(size_t)node * DIM + k];
                acc[nn].x += xv.x * w0.x + xv.y * w1.x + xv.z * w2.x + xv.w * w3.x;
                acc[nn].y += xv.x * w0.y + xv.y * w1.y + xv.z * w2.y + xv.w * w3.y;
                acc[nn].z += xv.x * w0.z + xv.y * w1.z + xv.z * w2.z + xv.w * w3.z;
                acc[nn].w += xv.x * w0.w + xv.y * w1.w + xv.z * w2.w + xv.w * w3.w;
            }
        }
    }
    #pragma unroll
    for (int nn = 0; nn < 8; nn++) {
        int node = node0 + nn;
        if (node < N_NODES) *(float4*)&xw[(size_t)node * DIM + ch] = acc[nn];
    }
}

// ---------------- fusion gather: one wave per selected node ----------------

__global__ void fuse_gather_kernel(const float* __restrict__ xw, const int* __restrict__ perm,
                                   const int* __restrict__ rowoff, const int* __restrict__ deg,
                                   const int* __restrict__ csr_src, const double* __restrict__ dinv,
                                   const float* __restrict__ scoref, const float* __restrict__ b_fu,
                                   float* __restrict__ out, long o0, long o4) {
    int gid  = blockIdx.x * blockDim.x + threadIdx.x;
    int wave = gid >> 6;
    int lane = threadIdx.x & 63;
    if (wave >= NGRAPH * KSEL) return;
    int p = perm[wave];
    double dp = dinv[p];
    int c2 = lane * 2;
    float2 v = ((const float2*)(xw + (size_t)p * DIM))[lane];
    float nself = (float)(dp * dp);
    float ax = nself * v.x, ay = nself * v.y;
    int beg = rowoff[p], cnt = deg[p];
    for (int e = 0; e < cnt; e++) {
        int s = csr_src[beg + e];
        float nf = (float)(dinv[s] * dp);
        float2 u = ((const float2*)(xw + (size_t)s * DIM))[lane];
        ax += nf * u.x;
        ay += nf * u.y;
    }
    ax += b_fu[c2];
    ay += b_fu[c2 + 1];
    float sc = scoref[p];
    size_t ro = (size_t)wave * DIM + c2;
    out[o4 + ro]     = ax;        // x_ae
    out[o4 + ro + 1] = ay;
    out[o0 + ro]     = ax * sc;   // x_out
    out[o0 + ro + 1] = ay * sc;
}

// ---------------- host ----------------

extern "C" void kernel_launch(void* const* d_in, const int* in_sizes, int n_in,
                              void* d_out, int out_size, void* d_ws, size_t ws_size,
                              hipStream_t stream) {
    const float* x    = (const float*)d_in[0];
    const int*   ei   = (const int*)d_in[1];
    const int*   src  = ei;
    const int*   dst  = ei + N_EDGES;
    const int*   batch= (const int*)d_in[2];
    const float* W_s  = (const float*)d_in[3];
    const float* b_s  = (const float*)d_in[4];
    const float* W_f  = (const float*)d_in[5];
    const float* b_f  = (const float*)d_in[6];
    const float* W_fu = (const float*)d_in[7];
    const float* b_fu = (const float*)d_in[8];
    float* out = (float*)d_out;

    // workspace carve-up (256B aligned regions)
    char* wsp = (char*)d_ws;
    size_t off = 0;
    auto take = [&](size_t bytes) -> char* {
        char* p = wsp + off;
        off = (off + bytes + 255) & ~(size_t)255;
        return p;
    };
    double* dinv     = (double*)take((size_t)N_NODES * 8);
    double* score_sd = (double*)take((size_t)N_NODES * 8);  // accum, then final f64 score
    double* xw_s     = (double*)take((size_t)N_NODES * 8);
    double* sf       = (double*)take((size_t)N_NODES * 8);
    float*  scoref   = (float*) take((size_t)N_NODES * 4);
    int*    deg      = (int*)   take((size_t)N_NODES * 4);
    int*    perm     = (int*)   take((size_t)NGRAPH * KSEL * 4);
    int*    nodemap  = (int*)   take((size_t)N_NODES * 4);
    int*    rowoff   = (int*)   take((size_t)N_NODES * 4);
    int*    cursor   = (int*)   take((size_t)N_NODES * 4);
    int*    epos     = (int*)   take((size_t)N_EDGES * 4);
    int*    bsums    = (int*)   take((size_t)SCAN_B * 4);
    int*    csr_src  = (int*)   take((size_t)N_EDGES * 4);
    float*  xw       = (float*) take((size_t)N_NODES * DIM * 4);

    // output layout: x_out[25000*128] | edge_index_new[2*M] | batch_out[25000] | perm[25000] | x_ae[25000*128]
    long M  = ((long)out_size - 6450000L) / 2;
    long o1 = 3200000L;
    long o2 = o1 + 2 * M;
    long o3 = o2 + (long)NGRAPH * KSEL;
    long o4 = o3 + (long)NGRAPH * KSEL;

    hipMemsetAsync(deg,      0,    (size_t)N_NODES * 4, stream);
    hipMemsetAsync(score_sd, 0,    (size_t)N_NODES * 8, stream);
    hipMemsetAsync(nodemap,  0xFF, (size_t)N_NODES * 4, stream);  // -1
    hipMemsetAsync(cursor,   0,    (size_t)N_NODES * 4, stream);

    const int TB = 256;
    int gE = (N_EDGES + TB - 1) / TB;
    int gN = (N_NODES + TB - 1) / TB;

    deg_kernel<<<gE, TB, 0, stream>>>(dst, deg);
    dinv_kernel<<<gN, TB, 0, stream>>>(deg, dinv);
    dots_kernel<<<(N_NODES * 64) / TB, TB, 0, stream>>>(x, W_s, W_f, b_f, xw_s, sf);
    score_edge_kernel<<<gE, TB, 0, stream>>>(src, dst, dinv, xw_s, score_sd);
    score_finalize_kernel<<<gN, TB, 0, stream>>>(dinv, xw_s, sf, b_s, score_sd, scoref);

    topk_kernel<<<NGRAPH, 512, 0, stream>>>(score_sd, batch, perm, nodemap, out, o2, o3);

    // edge compaction (order-preserving)
    int nbE = (N_EDGES + SCAN_B - 1) / SCAN_B;   // 489
    edge_flags_kernel<<<gE, TB, 0, stream>>>(src, dst, nodemap, epos);
    scan_block_kernel<<<nbE, SCAN_B, 0, stream>>>(epos, epos, bsums, N_EDGES);
    scan_sums_kernel<<<1, SCAN_B, 0, stream>>>(bsums, nbE);
    scan_add_kernel<<<gE, TB, 0, stream>>>(epos, bsums, N_EDGES);
    edge_scatter_kernel<<<gE, TB, 0, stream>>>(src, dst, nodemap, epos, out + o1, M);

    // CSR by dst
    int nbN = (N_NODES + SCAN_B - 1) / SCAN_B;   // 49
    scan_block_kernel<<<nbN, SCAN_B, 0, stream>>>(deg, rowoff, bsums, N_NODES);
    scan_sums_kernel<<<1, SCAN_B, 0, stream>>>(bsums, nbN);
    scan_add_kernel<<<gN, TB, 0, stream>>>(rowoff, bsums, N_NODES);
    csr_fill_kernel<<<gE, TB, 0, stream>>>(src, dst, rowoff, cursor, csr_src);

    // fusion conv
    gemm_xw_kernel<<<(N_NODES + 63) / 64, TB, 0, stream>>>(x, W_fu, xw);
    fuse_gather_kernel<<<(NGRAPH * KSEL * 64) / TB, TB, 0, stream>>>(
        xw, perm, rowoff, deg, csr_src, dinv, scoref, b_fu, out, 0L, o4);
}